// Round 1
// baseline (115.035 us; speedup 1.0000x reference)
//
#include <hip/hip_runtime.h>
#include <float.h>

constexpr int Bn = 8, Qn = 32768, Tn = 64, MT = 4;
constexpr int BLOCK = 256;

// compare-exchange on (val, idx) pairs, lexicographic (val, then idx) -> stable top_k tie-break
__device__ __forceinline__ void cmpx(float& av, int& ai, float& bv, int& bi) {
    bool sw = (bv < av) || ((bv == av) && (bi < ai));
    float v0 = sw ? bv : av; int i0 = sw ? bi : ai;
    float v1 = sw ? av : bv; int i1 = sw ? ai : bi;
    av = v0; ai = i0; bv = v1; bi = i1;
}

// a and b each sorted ascending (4 entries); leaves the 4 smallest of the union
// in a, sorted ascending. Uses min(a_k, b_{3-k}) (bitonic) + 4-element bitonic merge.
__device__ __forceinline__ void merge4(float a_v[4], int a_i[4],
                                       const float b_v[4], const int b_i[4]) {
    float mv[4]; int mi[4];
#pragma unroll
    for (int k = 0; k < 4; ++k) {
        float bv = b_v[3 - k]; int bi = b_i[3 - k];
        bool ta = (a_v[k] < bv) || ((a_v[k] == bv) && (a_i[k] < bi));
        mv[k] = ta ? a_v[k] : bv;
        mi[k] = ta ? a_i[k] : bi;
    }
    cmpx(mv[0], mi[0], mv[2], mi[2]);
    cmpx(mv[1], mi[1], mv[3], mi[3]);
    cmpx(mv[0], mi[0], mv[1], mi[1]);
    cmpx(mv[2], mi[2], mv[3], mi[3]);
#pragma unroll
    for (int k = 0; k < 4; ++k) { a_v[k] = mv[k]; a_i[k] = mi[k]; }
}

__global__ __launch_bounds__(BLOCK) void matcher_topk_kernel(
        const float* __restrict__ pred, const float* __restrict__ anch,
        const float* __restrict__ gt, int* __restrict__ out_i, int* __restrict__ out_j) {
    const int t     = blockIdx.x;   // target, fastest-varying -> same-slab blocks spread over XCDs
    const int which = blockIdx.y;   // 0 = pred_boxes, 1 = anchors
    const int b     = blockIdx.z;
    const int tid   = threadIdx.x;

    // gt box -> cxcywh (uniform across block; cached)
    const float4 g = *(const float4*)(gt + ((size_t)b * Tn + t) * 4);
    const float gcx = (g.x + g.z) * 0.5f;
    const float gcy = (g.y + g.w) * 0.5f;
    const float gw  = g.z - g.x;
    const float gh  = g.w - g.y;

    const float* boxes = which ? anch : pred;
    const float4* bp = (const float4*)(boxes + (size_t)b * Qn * 4);

    // per-thread sorted top-4 (ascending). Strict '<' + increasing q = stable tie-break.
    float v[4]  = {FLT_MAX, FLT_MAX, FLT_MAX, FLT_MAX};
    int   ix[4] = {0x7fffffff, 0x7fffffff, 0x7fffffff, 0x7fffffff};

    for (int q = tid; q < Qn; q += BLOCK) {
        float4 p = bp[q];
        float cx = (p.x + p.z) * 0.5f;
        float cy = (p.y + p.w) * 0.5f;
        float w  = p.z - p.x;
        float h  = p.w - p.y;
        // match jnp.sum(|.|, -1) sequential association
        float c = fabsf(cx - gcx) + fabsf(cy - gcy);
        c += fabsf(w - gw);
        c += fabsf(h - gh);
        if (c < v[3]) {
            if (c < v[2]) {
                v[3] = v[2]; ix[3] = ix[2];
                if (c < v[1]) {
                    v[2] = v[1]; ix[2] = ix[1];
                    if (c < v[0]) {
                        v[1] = v[0]; ix[1] = ix[0];
                        v[0] = c; ix[0] = q;
                    } else { v[1] = c; ix[1] = q; }
                } else { v[2] = c; ix[2] = q; }
            } else { v[3] = c; ix[3] = q; }
        }
    }

    // 64-lane butterfly merge: after this every lane holds the wave-wide top-4
#pragma unroll
    for (int d = 1; d < 64; d <<= 1) {
        float bv[4]; int bi[4];
#pragma unroll
        for (int k = 0; k < 4; ++k) {
            bv[k] = __shfl_xor(v[k], d, 64);
            bi[k] = __shfl_xor(ix[k], d, 64);
        }
        merge4(v, ix, bv, bi);
    }

    // cross-wave merge (4 waves) via LDS
    __shared__ float sv[4][4];
    __shared__ int   si[4][4];
    const int wave = tid >> 6;
    if ((tid & 63) == 0) {
#pragma unroll
        for (int k = 0; k < 4; ++k) { sv[wave][k] = v[k]; si[wave][k] = ix[k]; }
    }
    __syncthreads();
    if (tid == 0) {
#pragma unroll
        for (int wv = 1; wv < 4; ++wv) {
            float bv[4]; int bi[4];
#pragma unroll
            for (int k = 0; k < 4; ++k) { bv[k] = sv[wv][k]; bi[k] = si[wv][k]; }
            merge4(v, ix, bv, bi);
        }
        // idx_i layout: [B, T*2*MT], per (b,t): 4 pred-based then 4 anchor-based
        const int base = ((b * Tn + t) * 2 + which) * MT;
#pragma unroll
        for (int k = 0; k < 4; ++k) {
            out_i[base + k] = ix[k];
            out_j[base + k] = k;   // tile([0..3, 0..3], T)
        }
    }
}

extern "C" void kernel_launch(void* const* d_in, const int* in_sizes, int n_in,
                              void* d_out, int out_size, void* d_ws, size_t ws_size,
                              hipStream_t stream) {
    const float* pred = (const float*)d_in[0];
    const float* anch = (const float*)d_in[1];
    const float* gt   = (const float*)d_in[2];
    int* out = (int*)d_out;
    const int half = Bn * Tn * 2 * MT;  // 4096: idx_i block, then idx_j block
    dim3 grid(Tn, 2, Bn);
    matcher_topk_kernel<<<grid, BLOCK, 0, stream>>>(pred, anch, gt, out, out + half);
}

// Round 2
// 86.007 us; speedup vs baseline: 1.3375x; 1.3375x over previous
//
#include <hip/hip_runtime.h>
#include <float.h>

constexpr int Bn = 8, Qn = 32768, Tn = 64, MT = 4;
constexpr int BLOCK = 256;
constexpr int CHUNKS = 64;              // Q-chunks per (b,which); = 64 so stage2 lane <-> chunk
constexpr int CHUNK  = Qn / CHUNKS;     // 512 boxes per block
constexpr int PARTS  = BLOCK / 64;      // 4 waves per block
constexpr int SUB    = CHUNK / PARTS;   // 128 boxes scanned per wave

// compare-exchange on (val, idx), lexicographic -> stable top_k tie-break
__device__ __forceinline__ void cmpx(float& av, int& ai, float& bv, int& bi) {
    bool sw = (bv < av) || ((bv == av) && (bi < ai));
    float v0 = sw ? bv : av; int i0 = sw ? bi : ai;
    float v1 = sw ? av : bv; int i1 = sw ? ai : bi;
    av = v0; ai = i0; bv = v1; bi = i1;
}

// both lists sorted ascending; leaves 4 smallest of union in a, sorted.
__device__ __forceinline__ void merge4(float a_v[4], int a_i[4],
                                       const float b_v[4], const int b_i[4]) {
    float mv[4]; int mi[4];
#pragma unroll
    for (int k = 0; k < 4; ++k) {
        float bv = b_v[3 - k]; int bi = b_i[3 - k];
        bool ta = (a_v[k] < bv) || ((a_v[k] == bv) && (a_i[k] < bi));
        mv[k] = ta ? a_v[k] : bv;
        mi[k] = ta ? a_i[k] : bi;
    }
    cmpx(mv[0], mi[0], mv[2], mi[2]);
    cmpx(mv[1], mi[1], mv[3], mi[3]);
    cmpx(mv[0], mi[0], mv[1], mi[1]);
    cmpx(mv[2], mi[2], mv[3], mi[3]);
#pragma unroll
    for (int k = 0; k < 4; ++k) { a_v[k] = mv[k]; a_i[k] = mi[k]; }
}

// Stage 1: block = (chunk c, which, b). Lane = target, wave = quarter of chunk.
// Each box loaded from HBM once per block, converted once, broadcast from LDS.
__global__ __launch_bounds__(BLOCK) void matcher_stage1(
        const float* __restrict__ pred, const float* __restrict__ anch,
        const float* __restrict__ gt, float2* __restrict__ partial) {
    const int c     = blockIdx.x;
    const int which = blockIdx.y;
    const int b     = blockIdx.z;
    const int tid   = threadIdx.x;

    __shared__ float4 sbox[CHUNK];              // 8 KB: cxcywh-converted boxes
    __shared__ float2 sred[PARTS][64][4];       // 8 KB: cross-wave reduction

    const float4* bp = (const float4*)((which ? anch : pred) + (size_t)b * Qn * 4)
                       + (size_t)c * CHUNK;
    // cooperative load + convert (coalesced 16 B/lane)
#pragma unroll
    for (int i = tid; i < CHUNK; i += BLOCK) {
        float4 p = bp[i];
        sbox[i] = make_float4((p.x + p.z) * 0.5f, (p.y + p.w) * 0.5f,
                              p.z - p.x, p.w - p.y);
    }

    const int t    = tid & 63;     // this lane's target
    const int part = tid >> 6;     // this wave's sub-range of the chunk
    const float4 g = *(const float4*)(gt + ((size_t)b * Tn + t) * 4);
    const float gcx = (g.x + g.z) * 0.5f;
    const float gcy = (g.y + g.w) * 0.5f;
    const float gw  = g.z - g.x;
    const float gh  = g.w - g.y;

    __syncthreads();

    float v[4]  = {FLT_MAX, FLT_MAX, FLT_MAX, FLT_MAX};
    int   ix[4] = {0x7fffffff, 0x7fffffff, 0x7fffffff, 0x7fffffff};

    const int j0 = part * SUB;
    const int qbase = c * CHUNK + j0;
#pragma unroll 4
    for (int jj = 0; jj < SUB; ++jj) {
        float4 p = sbox[j0 + jj];              // wave-uniform addr -> LDS broadcast
        float cst = fabsf(p.x - gcx) + fabsf(p.y - gcy);
        cst += fabsf(p.z - gw);
        cst += fabsf(p.w - gh);
        const int q = qbase + jj;
        // branchless sorted insert; strict '<' keeps earlier idx on ties
        bool b3 = cst < v[3], b2 = cst < v[2], b1 = cst < v[1], b0 = cst < v[0];
        v[3] = b2 ? v[2] : (b3 ? cst : v[3]);  ix[3] = b2 ? ix[2] : (b3 ? q : ix[3]);
        v[2] = b1 ? v[1] : (b2 ? cst : v[2]);  ix[2] = b1 ? ix[1] : (b2 ? q : ix[2]);
        v[1] = b0 ? v[0] : (b1 ? cst : v[1]);  ix[1] = b0 ? ix[0] : (b1 ? q : ix[1]);
        v[0] = b0 ? cst : v[0];                ix[0] = b0 ? q    : ix[0];
    }

    // cross-wave (4 parts) merge per target via LDS
#pragma unroll
    for (int k = 0; k < 4; ++k)
        sred[part][t][k] = make_float2(v[k], __int_as_float(ix[k]));
    __syncthreads();

    if (tid < 64) {   // wave 0: lane = t; its own part-0 list already in v/ix
#pragma unroll
        for (int p2 = 1; p2 < PARTS; ++p2) {
            float bv[4]; int bi[4];
#pragma unroll
            for (int k = 0; k < 4; ++k) {
                float2 e = sred[p2][t][k];
                bv[k] = e.x; bi[k] = __float_as_int(e.y);
            }
            merge4(v, ix, bv, bi);
        }
        const int bw = b * 2 + which;
        float2* dst = partial + (((size_t)bw * 64 + t) * CHUNKS + c) * 4;
#pragma unroll
        for (int k = 0; k < 4; ++k)
            dst[k] = make_float2(v[k], __int_as_float(ix[k]));
    }
}

// Stage 2: one wave per (b,which,t); lane = chunk; 6-step butterfly merge.
__global__ __launch_bounds__(BLOCK) void matcher_stage2(
        const float2* __restrict__ partial,
        int* __restrict__ out_i, int* __restrict__ out_j) {
    const int lane = threadIdx.x & 63;
    const int gwv  = blockIdx.x * (BLOCK / 64) + (threadIdx.x >> 6); // tuple 0..1023
    const int bw = gwv >> 6;
    const int t  = gwv & 63;

    const float2* src = partial + (((size_t)bw * 64 + t) * CHUNKS + lane) * 4;
    float v[4]; int ix[4];
#pragma unroll
    for (int k = 0; k < 4; ++k) {
        float2 e = src[k];
        v[k] = e.x; ix[k] = __float_as_int(e.y);
    }
#pragma unroll
    for (int d = 1; d < 64; d <<= 1) {
        float bv[4]; int bi[4];
#pragma unroll
        for (int k = 0; k < 4; ++k) {
            bv[k] = __shfl_xor(v[k], d, 64);
            bi[k] = __shfl_xor(ix[k], d, 64);
        }
        merge4(v, ix, bv, bi);
    }
    if (lane == 0) {
        const int b = bw >> 1, which = bw & 1;
        const int base = ((b * Tn + t) * 2 + which) * MT;
#pragma unroll
        for (int k = 0; k < 4; ++k) {
            out_i[base + k] = ix[k];
            out_j[base + k] = k;
        }
    }
}

extern "C" void kernel_launch(void* const* d_in, const int* in_sizes, int n_in,
                              void* d_out, int out_size, void* d_ws, size_t ws_size,
                              hipStream_t stream) {
    const float* pred = (const float*)d_in[0];
    const float* anch = (const float*)d_in[1];
    const float* gt   = (const float*)d_in[2];
    int* out = (int*)d_out;
    float2* partial = (float2*)d_ws;   // 16*64*64*4 float2 = 2 MB
    const int half = Bn * Tn * 2 * MT; // 4096: idx_i block then idx_j block

    dim3 grid1(CHUNKS, 2, Bn);         // 1024 blocks
    matcher_stage1<<<grid1, BLOCK, 0, stream>>>(pred, anch, gt, partial);

    const int tuples = Bn * 2 * Tn;    // 1024 waves
    dim3 grid2(tuples / (BLOCK / 64)); // 256 blocks
    matcher_stage2<<<grid2, BLOCK, 0, stream>>>(partial, out, out + half);
}

// Round 3
// 83.041 us; speedup vs baseline: 1.3853x; 1.0357x over previous
//
#include <hip/hip_runtime.h>
#include <float.h>

constexpr int Bn = 8, Qn = 32768, Tn = 64, MT = 4;
constexpr int BLOCK = 256;
constexpr int CHUNKS = 64;              // Q-chunks per (b,which); = 64 so stage2 lane <-> chunk
constexpr int CHUNK  = Qn / CHUNKS;     // 512 boxes per block
constexpr int PARTS  = BLOCK / 64;      // 4 waves per block
constexpr int SUB    = CHUNK / PARTS;   // 128 boxes scanned per wave

// compare-exchange on (val, idx), lexicographic -> stable top_k tie-break (cold path)
__device__ __forceinline__ void cmpx(float& av, int& ai, float& bv, int& bi) {
    bool sw = (bv < av) || ((bv == av) && (bi < ai));
    float v0 = sw ? bv : av; int i0 = sw ? bi : ai;
    float v1 = sw ? av : bv; int i1 = sw ? ai : bi;
    av = v0; ai = i0; bv = v1; bi = i1;
}

// both lists sorted ascending; leaves 4 smallest of union in a, sorted. (cold path)
__device__ __forceinline__ void merge4(float a_v[4], int a_i[4],
                                       const float b_v[4], const int b_i[4]) {
    float mv[4]; int mi[4];
#pragma unroll
    for (int k = 0; k < 4; ++k) {
        float bv = b_v[3 - k]; int bi = b_i[3 - k];
        bool ta = (a_v[k] < bv) || ((a_v[k] == bv) && (a_i[k] < bi));
        mv[k] = ta ? a_v[k] : bv;
        mi[k] = ta ? a_i[k] : bi;
    }
    cmpx(mv[0], mi[0], mv[2], mi[2]);
    cmpx(mv[1], mi[1], mv[3], mi[3]);
    cmpx(mv[0], mi[0], mv[1], mi[1]);
    cmpx(mv[2], mi[2], mv[3], mi[3]);
#pragma unroll
    for (int k = 0; k < 4; ++k) { a_v[k] = mv[k]; a_i[k] = mi[k]; }
}

// Stage 1: block = (chunk c, which, b). Lane = target, wave = quarter of chunk.
// Boxes loaded from HBM once per block, converted once, broadcast from LDS.
__global__ __launch_bounds__(BLOCK) void matcher_stage1(
        const float* __restrict__ pred, const float* __restrict__ anch,
        const float* __restrict__ gt, float2* __restrict__ partial) {
    const int c     = blockIdx.x;
    const int which = blockIdx.y;
    const int b     = blockIdx.z;
    const int tid   = threadIdx.x;

    __shared__ float4 sbox[CHUNK];              // 8 KB: cxcywh-converted boxes
    __shared__ float2 sred[PARTS][64][5];       // pad 4->5: break 16-way write conflict

    const float4* bp = (const float4*)((which ? anch : pred) + (size_t)b * Qn * 4)
                       + (size_t)c * CHUNK;
#pragma unroll
    for (int i = tid; i < CHUNK; i += BLOCK) {
        float4 p = bp[i];
        sbox[i] = make_float4((p.x + p.z) * 0.5f, (p.y + p.w) * 0.5f,
                              p.z - p.x, p.w - p.y);
    }

    const int t    = tid & 63;     // this lane's target
    const int part = tid >> 6;     // this wave's sub-range of the chunk
    const float4 g = *(const float4*)(gt + ((size_t)b * Tn + t) * 4);
    const float gcx = (g.x + g.z) * 0.5f;
    const float gcy = (g.y + g.w) * 0.5f;
    const float gw  = g.z - g.x;
    const float gh  = g.w - g.y;

    __syncthreads();

    float v[4]  = {FLT_MAX, FLT_MAX, FLT_MAX, FLT_MAX};
    int   ix[4] = {0x7fffffff, 0x7fffffff, 0x7fffffff, 0x7fffffff};

    const int j0 = part * SUB;
    const int qbase = c * CHUNK + j0;
#pragma unroll 8
    for (int jj = 0; jj < SUB; ++jj) {
        float4 p = sbox[j0 + jj];              // wave-uniform addr -> LDS broadcast
        float d0 = p.x - gcx, d1 = p.y - gcy, d2 = p.z - gw, d3 = p.w - gh;
        float cst = fabsf(d0) + fabsf(d1);     // abs folds into VOP3 src modifiers
        cst += fabsf(d2);
        cst += fabsf(d3);
        const int q = qbase + jj;
        // values: compare-free sorted insert via min/med3
        float n0 = fminf(v[0], cst);
        float n1 = __builtin_amdgcn_fmed3f(v[0], v[1], cst);
        float n2 = __builtin_amdgcn_fmed3f(v[1], v[2], cst);
        float n3 = __builtin_amdgcn_fmed3f(v[2], v[3], cst);
        // indices: strict '<' keeps earlier idx on exact ties (top_k stability)
        bool b0 = cst < v[0], b1 = cst < v[1], b2 = cst < v[2], b3 = cst < v[3];
        int i3 = b2 ? ix[2] : (b3 ? q : ix[3]);
        int i2 = b1 ? ix[1] : (b2 ? q : ix[2]);
        int i1 = b0 ? ix[0] : (b1 ? q : ix[1]);
        int i0 = b0 ? q : ix[0];
        v[0] = n0; v[1] = n1; v[2] = n2; v[3] = n3;
        ix[0] = i0; ix[1] = i1; ix[2] = i2; ix[3] = i3;
    }

    // cross-wave (4 parts) merge per target via LDS
#pragma unroll
    for (int k = 0; k < 4; ++k)
        sred[part][t][k] = make_float2(v[k], __int_as_float(ix[k]));
    __syncthreads();

    if (tid < 64) {   // wave 0: lane = t; its own part-0 list already in v/ix
#pragma unroll
        for (int p2 = 1; p2 < PARTS; ++p2) {
            float bv[4]; int bi[4];
#pragma unroll
            for (int k = 0; k < 4; ++k) {
                float2 e = sred[p2][t][k];
                bv[k] = e.x; bi[k] = __float_as_int(e.y);
            }
            merge4(v, ix, bv, bi);
        }
        // layout [bw][chunk][t][4] -> this wave's 64 lanes write one contiguous 2 KB run
        const int bw = b * 2 + which;
        float2* dst = partial + (((size_t)bw * CHUNKS + c) * 64 + t) * 4;
#pragma unroll
        for (int k = 0; k < 4; ++k)
            dst[k] = make_float2(v[k], __int_as_float(ix[k]));
    }
}

// Stage 2: one wave per (b,which,t); lane = chunk; 6-step butterfly merge.
__global__ __launch_bounds__(BLOCK) void matcher_stage2(
        const float2* __restrict__ partial,
        int* __restrict__ out_i, int* __restrict__ out_j) {
    const int lane = threadIdx.x & 63;
    const int gwv  = blockIdx.x * (BLOCK / 64) + (threadIdx.x >> 6); // tuple 0..1023
    const int bw = gwv >> 6;
    const int t  = gwv & 63;

    // partial layout: [bw][chunk][t][4]; this lane's chunk = lane
    const float4* src4 = (const float4*)(partial + (((size_t)bw * CHUNKS + lane) * 64 + t) * 4);
    float4 e0 = src4[0], e1 = src4[1];     // 2x dwordx4 instead of 4x dwordx2
    float v[4]; int ix[4];
    v[0] = e0.x; ix[0] = __float_as_int(e0.y);
    v[1] = e0.z; ix[1] = __float_as_int(e0.w);
    v[2] = e1.x; ix[2] = __float_as_int(e1.y);
    v[3] = e1.z; ix[3] = __float_as_int(e1.w);

#pragma unroll
    for (int d = 1; d < 64; d <<= 1) {
        float bv[4]; int bi[4];
#pragma unroll
        for (int k = 0; k < 4; ++k) {
            bv[k] = __shfl_xor(v[k], d, 64);
            bi[k] = __shfl_xor(ix[k], d, 64);
        }
        merge4(v, ix, bv, bi);
    }
    if (lane == 0) {
        const int b = bw >> 1, which = bw & 1;
        const int base = ((b * Tn + t) * 2 + which) * MT;
#pragma unroll
        for (int k = 0; k < 4; ++k) {
            out_i[base + k] = ix[k];
            out_j[base + k] = k;
        }
    }
}

extern "C" void kernel_launch(void* const* d_in, const int* in_sizes, int n_in,
                              void* d_out, int out_size, void* d_ws, size_t ws_size,
                              hipStream_t stream) {
    const float* pred = (const float*)d_in[0];
    const float* anch = (const float*)d_in[1];
    const float* gt   = (const float*)d_in[2];
    int* out = (int*)d_out;
    float2* partial = (float2*)d_ws;   // 16*64*64*4 float2 = 2 MB
    const int half = Bn * Tn * 2 * MT; // 4096: idx_i block then idx_j block

    dim3 grid1(CHUNKS, 2, Bn);         // 1024 blocks
    matcher_stage1<<<grid1, BLOCK, 0, stream>>>(pred, anch, gt, partial);

    const int tuples = Bn * 2 * Tn;    // 1024 waves
    dim3 grid2(tuples / (BLOCK / 64)); // 256 blocks
    matcher_stage2<<<grid2, BLOCK, 0, stream>>>(partial, out, out + half);
}